// Round 8
// baseline (669.537 us; speedup 1.0000x reference)
//
#include <hip/hip_runtime.h>
#include <math.h>

// ---------------------------------------------------------------------------
// MultiModalGraphSAGE — R14.
// R13 post-mortem: relcls fusion neutral -> launches/mid intermediates are
// not the cost. Budget: s0/st GEMMs each re-stage the A row-panel once per
// col-block (grid.x=4 -> 204MB L3 traffic each). R14: widen the inner GEMM
// to NT=8 (grid.x=2) with 512 threads / 8 waves (2m x 4n) and 96KB LDS —
// same 8 waves/CU as before (was 2 blocks x 4 waves), half the A-restage.
// Staging 6 loads/thread/K-step, counted vmcnt(6). Numerics identical.
// enc (at ~97% of the observed ~2.2TB/s environmental HBM ceiling), aggs,
// CSR, relcls unchanged.
// ---------------------------------------------------------------------------

#define EPS 1e-5f

typedef __attribute__((ext_vector_type(8))) short bf16x8;
typedef __attribute__((ext_vector_type(4))) float f32x4;

__device__ inline unsigned short f2bf(float x) {
    unsigned u = __float_as_uint(x);
    u += 0x7fff + ((u >> 16) & 1);          // RNE to bf16
    return (unsigned short)(u >> 16);
}
__device__ inline float bf2f(unsigned short h) {
    return __uint_as_float(((unsigned)h) << 16);
}
__device__ inline unsigned packbf(float x, float y) {
    return (unsigned)f2bf(x) | ((unsigned)f2bf(y) << 16);
}

__device__ inline void gload_lds16(const void* g, void* l) {
    __builtin_amdgcn_global_load_lds(
        (__attribute__((address_space(1))) void*)g,
        (__attribute__((address_space(3))) void*)l, 16, 0, 0);
}

// ---------------- CSR build ----------------

__global__ void count_deg(const int* __restrict__ dst, int* __restrict__ deg, int e) {
    int i = blockIdx.x * 256 + threadIdx.x;
    if (i < e) atomicAdd(&deg[dst[i]], 1);
}

__global__ __launch_bounds__(1024)
void scan_block(const int* __restrict__ deg, int* __restrict__ rowptr,
                int* __restrict__ part, int n) {
    __shared__ int buf[1024];
    const int tid = threadIdx.x;
    const int i = blockIdx.x * 1024 + tid;
    const int v = (i < n) ? deg[i] : 0;
    buf[tid] = v;
    __syncthreads();
    #pragma unroll 1
    for (int off = 1; off < 1024; off <<= 1) {
        int t = (tid >= off) ? buf[tid - off] : 0;
        __syncthreads();
        buf[tid] += t;
        __syncthreads();
    }
    if (i < n) rowptr[i] = buf[tid] - v;          // local exclusive
    if (tid == 1023) part[blockIdx.x] = buf[1023];
}

__global__ __launch_bounds__(1024)
void scan_part(int* __restrict__ part, int nb) {
    __shared__ int buf[1024];
    const int tid = threadIdx.x;
    const int v = (tid < nb) ? part[tid] : 0;
    buf[tid] = v;
    __syncthreads();
    #pragma unroll 1
    for (int off = 1; off < 1024; off <<= 1) {
        int t = (tid >= off) ? buf[tid - off] : 0;
        __syncthreads();
        buf[tid] += t;
        __syncthreads();
    }
    if (tid < nb) part[tid] = buf[tid] - v;       // exclusive
    if (tid == 1023) part[nb] = buf[1023];        // grand total
}

__global__ void scan_add(const int* __restrict__ part, int* __restrict__ rowptr,
                         int* __restrict__ cursor, int n, int nb) {
    int i = blockIdx.x * 256 + threadIdx.x;
    if (i < n) {
        int v = rowptr[i] + part[i >> 10];
        rowptr[i] = v;
        cursor[i] = v;
    }
    if (i == 0) rowptr[n] = part[nb];
}

__global__ void fill_edges(const int* __restrict__ src, const int* __restrict__ dst,
                           int* __restrict__ cursor, int* __restrict__ eidx, int e) {
    int i = blockIdx.x * 256 + threadIdx.x;
    if (i < e) {
        int pos = atomicAdd(&cursor[dst[i]], 1);
        eidx[pos] = src[i];
    }
}

// ---------------- fused weight prep: all W[K][N] fp32 -> hi/lo [N][ldt] ----

__global__ __launch_bounds__(256)
void prep_all(const float* __restrict__ enc_w, const float* __restrict__ s0_ws,
              const float* __restrict__ s0_wn, const float* __restrict__ s1_ws,
              const float* __restrict__ s1_wn, const float* __restrict__ rel_w,
              const float* __restrict__ cw1, const float* __restrict__ cw2,
              short* wt_enc_h, short* wt_enc_l, short* wt_s0_h, short* wt_s0_l,
              short* wt_st_h, short* wt_st_l, short* wt_rel_h, short* wt_rel_l,
              short* wt_c1_h, short* wt_c1_l, short* wt_c2_h, short* wt_c2_l) {
    int e = blockIdx.x * 256 + threadIdx.x;
    const float* W; short* hi; short* lo; int Nd, ldt, koff;
    if (e < 65536)       { W = enc_w; hi = wt_enc_h; lo = wt_enc_l; Nd = 128; ldt = 512; koff = 0; }
    else if (e < 98304)  { e -= 65536;  W = s0_ws; hi = wt_s0_h; lo = wt_s0_l; Nd = 256; ldt = 256; koff = 0; }
    else if (e < 131072) { e -= 98304;  W = s0_wn; hi = wt_s0_h; lo = wt_s0_l; Nd = 256; ldt = 256; koff = 128; }
    else if (e < 163840) { e -= 131072; W = s1_ws; hi = wt_st_h; lo = wt_st_l; Nd = 128; ldt = 256; koff = 0; }
    else if (e < 196608) { e -= 163840; W = s1_wn; hi = wt_st_h + 32768; lo = wt_st_l + 32768; Nd = 128; ldt = 256; koff = 0; }
    else if (e < 229376) { e -= 196608; W = rel_w; hi = wt_rel_h; lo = wt_rel_l; Nd = 128; ldt = 256; koff = 0; }
    else if (e < 237568) { e -= 229376; W = cw1; hi = wt_c1_h; lo = wt_c1_l; Nd = 64; ldt = 128; koff = 0; }
    else if (e < 239616) { e -= 237568; W = cw2; hi = wt_c2_h; lo = wt_c2_l; Nd = 32; ldt = 64; koff = 0; }
    else return;
    const int k = e / Nd, n = e - k * Nd;
    const float x = W[e];
    const unsigned short h = f2bf(x);
    const unsigned short l = f2bf(x - bf2f(h));
    const size_t o = (size_t)n * ldt + koff + k;
    hi[o] = (short)h;
    lo[o] = (short)l;
}

// ---------------- mean aggregation: 2-edge ILP per 16-lane group ------------

__global__ __launch_bounds__(256)
void agg_mean_bb(const short* __restrict__ featb,
                 const int* __restrict__ rowptr, const int* __restrict__ eidx,
                 short* __restrict__ outb, int n) {
    const int node = blockIdx.x * 4 + (threadIdx.x >> 6);
    if (node >= n) return;
    const int lane = threadIdx.x & 63;
    const int g = lane >> 4, j = lane & 15;
    const int beg = rowptr[node], end = rowptr[node + 1];
    float s[8];
    #pragma unroll
    for (int i = 0; i < 8; ++i) s[i] = 0.f;
    for (int e = beg + g; e < end; e += 8) {
        const int e1 = e + 4;
        const bool has2 = e1 < end;
        const int i0 = eidx[e];
        const int i1 = has2 ? eidx[e1] : i0;
        const uint4 v0 = *(const uint4*)(featb + (size_t)i0 * 128 + j * 8);
        const uint4 v1 = *(const uint4*)(featb + (size_t)i1 * 128 + j * 8);
        __builtin_amdgcn_sched_barrier(0);
        s[0] += __uint_as_float(v0.x << 16); s[1] += __uint_as_float(v0.x & 0xffff0000u);
        s[2] += __uint_as_float(v0.y << 16); s[3] += __uint_as_float(v0.y & 0xffff0000u);
        s[4] += __uint_as_float(v0.z << 16); s[5] += __uint_as_float(v0.z & 0xffff0000u);
        s[6] += __uint_as_float(v0.w << 16); s[7] += __uint_as_float(v0.w & 0xffff0000u);
        if (has2) {
            s[0] += __uint_as_float(v1.x << 16); s[1] += __uint_as_float(v1.x & 0xffff0000u);
            s[2] += __uint_as_float(v1.y << 16); s[3] += __uint_as_float(v1.y & 0xffff0000u);
            s[4] += __uint_as_float(v1.z << 16); s[5] += __uint_as_float(v1.z & 0xffff0000u);
            s[6] += __uint_as_float(v1.w << 16); s[7] += __uint_as_float(v1.w & 0xffff0000u);
        }
    }
    #pragma unroll
    for (int i = 0; i < 8; ++i) {
        s[i] += __shfl_xor(s[i], 32);
        s[i] += __shfl_xor(s[i], 16);
    }
    if (g == 0) {
        const float inv = 1.0f / fmaxf((float)(end - beg), 1.0f);
        uint4 o;
        o.x = packbf(s[0] * inv, s[1] * inv);
        o.y = packbf(s[2] * inv, s[3] * inv);
        o.z = packbf(s[4] * inv, s[5] * inv);
        o.w = packbf(s[6] * inv, s[7] * inv);
        *(uint4*)(outb + (size_t)node * 128 + j * 8) = o;
    }
}

// sage1 combine: h2 = relu(bn1(s1 + mean_neigh(t1) + b1)), bf16 out
__global__ __launch_bounds__(256)
void agg_combine_bb(const short* __restrict__ featb,
                    const int* __restrict__ rowptr, const int* __restrict__ eidx,
                    const float* __restrict__ s1,          // [n,128] fp32
                    const float* __restrict__ bias,
                    const float* __restrict__ bng, const float* __restrict__ bnb,
                    const float* __restrict__ bnm, const float* __restrict__ bnv,
                    short* __restrict__ outb, int n) {
    const int node = blockIdx.x * 4 + (threadIdx.x >> 6);
    if (node >= n) return;
    const int lane = threadIdx.x & 63;
    const int g = lane >> 4, j = lane & 15;
    const int beg = rowptr[node], end = rowptr[node + 1];
    float s[8];
    #pragma unroll
    for (int i = 0; i < 8; ++i) s[i] = 0.f;
    for (int e = beg + g; e < end; e += 8) {
        const int e1 = e + 4;
        const bool has2 = e1 < end;
        const int i0 = eidx[e];
        const int i1 = has2 ? eidx[e1] : i0;
        const uint4 v0 = *(const uint4*)(featb + (size_t)i0 * 128 + j * 8);
        const uint4 v1 = *(const uint4*)(featb + (size_t)i1 * 128 + j * 8);
        __builtin_amdgcn_sched_barrier(0);
        s[0] += __uint_as_float(v0.x << 16); s[1] += __uint_as_float(v0.x & 0xffff0000u);
        s[2] += __uint_as_float(v0.y << 16); s[3] += __uint_as_float(v0.y & 0xffff0000u);
        s[4] += __uint_as_float(v0.z << 16); s[5] += __uint_as_float(v0.z & 0xffff0000u);
        s[6] += __uint_as_float(v0.w << 16); s[7] += __uint_as_float(v0.w & 0xffff0000u);
        if (has2) {
            s[0] += __uint_as_float(v1.x << 16); s[1] += __uint_as_float(v1.x & 0xffff0000u);
            s[2] += __uint_as_float(v1.y << 16); s[3] += __uint_as_float(v1.y & 0xffff0000u);
            s[4] += __uint_as_float(v1.z << 16); s[5] += __uint_as_float(v1.z & 0xffff0000u);
            s[6] += __uint_as_float(v1.w << 16); s[7] += __uint_as_float(v1.w & 0xffff0000u);
        }
    }
    #pragma unroll
    for (int i = 0; i < 8; ++i) {
        s[i] += __shfl_xor(s[i], 32);
        s[i] += __shfl_xor(s[i], 16);
    }
    if (g == 0) {
        const float inv = 1.0f / fmaxf((float)(end - beg), 1.0f);
        const int c0 = j * 8;
        const float4 a0 = *(const float4*)(s1 + (size_t)node * 128 + c0);
        const float4 a1 = *(const float4*)(s1 + (size_t)node * 128 + c0 + 4);
        const float sf[8] = {a0.x, a0.y, a0.z, a0.w, a1.x, a1.y, a1.z, a1.w};
        float r[8];
        #pragma unroll
        for (int i = 0; i < 8; ++i) {
            const int c = c0 + i;
            float v = sf[i] + s[i] * inv + bias[c];
            v = (v - bnm[c]) * (bng[c] / sqrtf(bnv[c] + EPS)) + bnb[c];
            r[i] = fmaxf(v, 0.f);
        }
        uint4 o;
        o.x = packbf(r[0], r[1]); o.y = packbf(r[2], r[3]);
        o.z = packbf(r[4], r[5]); o.w = packbf(r[6], r[7]);
        *(uint4*)(outb + (size_t)node * 128 + j * 8) = o;
    }
}

// ---------------- wide all-LDS MFMA GEMM: 512 thr, NT=8 (128 cols/block) ---
// 8 waves arranged 2m x 4n (wave = 64 rows x 32 cols). BK=64, double-buffered
// 96KB LDS. A+B staged by gload_lds16 (pre-XOR-swizzled source, linear LDS,
// swizzled ds_read). 6 loads/thread/K-step; counted vmcnt(6). Halves the
// per-GEMM A-restage vs the old NT=4/grid.x=4 layout (204 -> 102 MB).
template<int K1, int K2>
__global__ __launch_bounds__(512)
void gemm_w(const short* __restrict__ A1, int lda1,
            const short* __restrict__ A2, int lda2,
            const short* __restrict__ Wt_hi, const short* __restrict__ Wt_lo,
            const float* __restrict__ bias,
            const float* __restrict__ bng, const float* __restrict__ bnb,
            const float* __restrict__ bnm, const float* __restrict__ bnv,
            int relu,
            float* __restrict__ Cf, int fpN, int ldc,
            short* __restrict__ Cb, int bfcol0, int ldcb,
            int M) {
    constexpr int K   = K1 + K2;
    constexpr int NBK = K / 64;
    constexpr int NT  = 8, NTW = 2;
    static_assert(K % 64 == 0, "K multiple of 64");
    static_assert(K2 == 0 || K1 % 64 == 0, "concat boundary on BK");
    constexpr int ASZ = 128 * 64;                 // 16 KB
    constexpr int BSZ = 2 * NT * 16 * 64;         // 32 KB (hi+lo planes)
    constexpr int BUF = ASZ + BSZ;                // 24576 shorts
    __shared__ short lds[2 * BUF];                // 96 KB

    const int tid  = threadIdx.x;
    const int lane = tid & 63;
    const int wv   = tid >> 6;                    // 0..7
    const int wm   = wv >> 2;                     // 0..1 (row half)
    const int wn   = wv & 3;                      // 0..3 (col quarter)
    const int bm   = blockIdx.y * 128;
    const int col0 = blockIdx.x * 128;
    const int lrow = lane & 15;
    const int quad = lane >> 4;

    // staging sources: phys (row,u) holds global unit u^(row&7)
    const int su = (tid & 7) ^ ((tid >> 3) & 7);
    const short* gsA1[2];
    const short* gsA2[2];
    #pragma unroll
    for (int jj = 0; jj < 2; ++jj) {
        const int rg = min(bm + jj * 64 + (tid >> 3), M - 1);
        gsA1[jj] = A1 + (size_t)rg * lda1 + su * 8;
        if constexpr (K2 > 0) gsA2[jj] = A2 + (size_t)rg * lda2 + su * 8;
        else gsA2[jj] = nullptr;
    }
    const short* gsB[4];                          // 256 col-rows: hi then lo
    #pragma unroll
    for (int jj = 0; jj < 4; ++jj) {
        const int colIdx = jj * 64 + (tid >> 3);  // 0..255
        const bool ishi = colIdx < 128;
        const int cp = ishi ? colIdx : colIdx - 128;
        gsB[jj] = (ishi ? Wt_hi : Wt_lo) + (size_t)(col0 + cp) * K + su * 8;
    }

    auto stage = [&](int b, int c) {
        const int k = c * 64;
        #pragma unroll
        for (int jj = 0; jj < 2; ++jj) {
            const short* p;
            if constexpr (K2 > 0)
                p = (k < K1) ? (gsA1[jj] + k) : (gsA2[jj] + (k - K1));
            else
                p = gsA1[jj] + k;
            gload_lds16(p, &lds[b * BUF + (jj * 512 + tid) * 8]);
        }
        #pragma unroll
        for (int jj = 0; jj < 4; ++jj)
            gload_lds16(gsB[jj] + k, &lds[b * BUF + ASZ + (jj * 512 + tid) * 8]);
    };

    int aoff[4][2];
    #pragma unroll
    for (int m = 0; m < 4; ++m)
        #pragma unroll
        for (int kk = 0; kk < 2; ++kk)
            aoff[m][kk] = (wm * 64 + m * 16 + lrow) * 64 +
                          (((kk * 4 + quad) ^ (lrow & 7)) * 8);
    int boff[NTW][2];
    #pragma unroll
    for (int nt = 0; nt < NTW; ++nt)
        #pragma unroll
        for (int kk = 0; kk < 2; ++kk)
            boff[nt][kk] = (wn * 32 + nt * 16 + lrow) * 64 +
                           (((kk * 4 + quad) ^ (lrow & 7)) * 8);

    f32x4 acc[4][NTW];
    #pragma unroll
    for (int m = 0; m < 4; ++m)
        #pragma unroll
        for (int nt = 0; nt < NTW; ++nt)
            acc[m][nt] = (f32x4){0.f, 0.f, 0.f, 0.f};

    stage(0, 0);

    for (int c = 0; c < NBK; ++c) {
        const int b = c & 1;
        if (c + 1 < NBK) {
            stage(b ^ 1, c + 1);
            asm volatile("s_waitcnt vmcnt(6)" ::: "memory");
        } else {
            asm volatile("s_waitcnt vmcnt(0)" ::: "memory");
        }
        __builtin_amdgcn_s_barrier();             // buf b fully staged

        const short* La = &lds[b * BUF];
        const short* Lb = &lds[b * BUF + ASZ];
        #pragma unroll
        for (int kk = 0; kk < 2; ++kk) {
            bf16x8 a[4];
            #pragma unroll
            for (int m = 0; m < 4; ++m)
                a[m] = *(const bf16x8*)(La + aoff[m][kk]);
            #pragma unroll
            for (int nt = 0; nt < NTW; ++nt) {
                const bf16x8 vbh = *(const bf16x8*)(Lb + boff[nt][kk]);
                const bf16x8 vbl = *(const bf16x8*)(Lb + boff[nt][kk] + NT * 16 * 64);
                #pragma unroll
                for (int m = 0; m < 4; ++m) {
                    acc[m][nt] = __builtin_amdgcn_mfma_f32_16x16x32_bf16(a[m], vbh, acc[m][nt], 0, 0, 0);
                    acc[m][nt] = __builtin_amdgcn_mfma_f32_16x16x32_bf16(a[m], vbl, acc[m][nt], 0, 0, 0);
                }
            }
        }
        asm volatile("" ::: "memory");
        __builtin_amdgcn_s_barrier();             // all waves done with buf b
    }

    // ---- epilogue via LDS: coalesced stores ----
    constexpr int EW = 132;                       // 128 + 4 (16B-aligned)
    float* ep = (float*)lds;                      // 128*132*4 = 67.6 KB < 96

    #pragma unroll
    for (int nt = 0; nt < NTW; ++nt) {
        const int lcol = wn * 32 + nt * 16 + lrow;
        const int gcol = col0 + lcol;
        const float bsc = bias ? bias[gcol] : 0.f;
        float gg = 1.f, bb = 0.f, mm = 0.f;
        if (bng) { gg = bng[gcol] / sqrtf(bnv[gcol] + EPS); bb = bnb[gcol]; mm = bnm[gcol]; }
        #pragma unroll
        for (int m = 0; m < 4; ++m) {
            #pragma unroll
            for (int r = 0; r < 4; ++r) {
                float x = acc[m][nt][r] + bsc;
                if (bng) x = (x - mm) * gg + bb;
                if (relu) x = fmaxf(x, 0.f);
                ep[(wm * 64 + m * 16 + quad * 4 + r) * EW + lcol] = x;
            }
        }
    }
    __syncthreads();

    if (col0 < fpN) {                             // fp32-target block
        for (int g = tid; g < 128 * 32; g += 512) {
            const int row = g >> 5, u = g & 31;
            const int grow = bm + row;
            if (grow < M)
                *(float4*)(Cf + (size_t)grow * ldc + col0 + u * 4) =
                    *(const float4*)(ep + row * EW + u * 4);
        }
    } else {                                      // bf16-target block
        for (int g = tid; g < 128 * 16; g += 512) {
            const int row = g >> 4, u = g & 15;
            const int grow = bm + row;
            const float4 f0 = *(const float4*)(ep + row * EW + u * 8);
            const float4 f1 = *(const float4*)(ep + row * EW + u * 8 + 4);
            uint4 o;
            o.x = packbf(f0.x, f0.y); o.y = packbf(f0.z, f0.w);
            o.z = packbf(f1.x, f1.y); o.w = packbf(f1.z, f1.w);
            if (grow < M)
                *(uint4*)(Cb + (size_t)grow * ldcb + (col0 - bfcol0) + u * 8) = o;
        }
    }
}

// ---------------- fused enc GEMM: fp32 concat A -> bf16 staging -----------
__global__ __launch_bounds__(256)
void gemm_enc(const float* __restrict__ A1f,           // sf [M,128]
              const float* __restrict__ A2f,           // mf [M,384]
              const short* __restrict__ Wt_hi, const short* __restrict__ Wt_lo,
              const float* __restrict__ bias,
              short* __restrict__ Cb, int ldcb, int M) {
    constexpr int NT = 4, NTW = 2, K = 512, NBK = 8;
    constexpr int ASZ = 128 * 64;                 // shorts (16KB)
    constexpr int BSZ = 2 * NT * 16 * 64;         // shorts (16KB)
    constexpr int BUF = ASZ + BSZ;
    __shared__ short lds[2 * BUF];                // 64 KB

    const int tid  = threadIdx.x;
    const int lane = tid & 63;
    const int wv   = tid >> 6;
    const int wm   = wv >> 1;
    const int wn   = wv & 1;
    const int bm   = blockIdx.y * 128;
    const int col0 = blockIdx.x * (NT * 16);
    const int lrow = lane & 15;
    const int quad = lane >> 4;

    const int su = (tid & 7) ^ ((tid >> 3) & 7);
    const float* gsA1[4];
    const float* gsA2[4];
    #pragma unroll
    for (int jj = 0; jj < 4; ++jj) {
        const int rg = min(bm + jj * 32 + (tid >> 3), M - 1);
        gsA1[jj] = A1f + (size_t)rg * 128 + su * 8;
        gsA2[jj] = A2f + (size_t)rg * 384 + su * 8;
    }
    const short* gsB[NT];
    #pragma unroll
    for (int jj = 0; jj < NT; ++jj) {
        const int colIdx = jj * 32 + (tid >> 3);
        const bool ishi = colIdx < NT * 16;
        const int cp = ishi ? colIdx : colIdx - NT * 16;
        gsB[jj] = (ishi ? Wt_hi : Wt_lo) + (size_t)(col0 + cp) * K + su * 8;
    }
    auto stageB = [&](int b, int c) {
        const int k = c * 64;
        #pragma unroll
        for (int jj = 0; jj < NT; ++jj)
            gload_lds16(gsB[jj] + k, &lds[b * BUF + ASZ + (jj * 256 + tid) * 8]);
    };

    int aoff[4][2], boff[NTW][2];
    #pragma unroll
    for (int m = 0; m < 4; ++m)
        #pragma unroll
        for (int kk = 0; kk < 2; ++kk)
            aoff[m][kk] = (wm * 64 + m * 16 + lrow) * 64 +
                          (((kk * 4 + quad) ^ (lrow & 7)) * 8);
    #pragma unroll
    for (int nt = 0; nt < NTW; ++nt)
        #pragma unroll
        for (int kk = 0; kk < 2; ++kk)
            boff[nt][kk] = (wn * NTW * 16 + nt * 16 + lrow) * 64 +
                           (((kk * 4 + quad) ^ (lrow & 7)) * 8);

    f32x4 acc[4][NTW];
    #pragma unroll
    for (int m = 0; m < 4; ++m)
        #pragma unroll
        for (int nt = 0; nt < NTW; ++nt)
            acc[m][nt] = (f32x4){0.f, 0.f, 0.f, 0.f};

    float4 awin[8];

    #pragma unroll
    for (int jj = 0; jj < 4; ++jj) {
        awin[jj * 2 + 0] = *(const float4*)(gsA1[jj]);
        awin[jj * 2 + 1] = *(const float4*)(gsA1[jj] + 4);
    }
    stageB(0, 0);
    #pragma unroll
    for (int jj = 0; jj < 4; ++jj) {
        const float4 w0 = awin[jj * 2 + 0], w1 = awin[jj * 2 + 1];
        uint4 o;
        o.x = packbf(w0.x, w0.y); o.y = packbf(w0.z, w0.w);
        o.z = packbf(w1.x, w1.y); o.w = packbf(w1.z, w1.w);
        *((uint4*)&lds[(jj * 256 + tid) * 8]) = o;
    }
    asm volatile("s_waitcnt vmcnt(0)" ::: "memory");
    __builtin_amdgcn_s_barrier();

    #pragma unroll
    for (int c = 0; c < NBK; ++c) {
        const int cur = c & 1, nxt = cur ^ 1;
        if (c + 1 < NBK) {
            const int k1 = (c + 1) * 64;
            #pragma unroll
            for (int jj = 0; jj < 4; ++jj) {
                const float* p = (k1 < 128) ? (gsA1[jj] + k1)
                                            : (gsA2[jj] + (k1 - 128));
                awin[jj * 2 + 0] = *(const float4*)p;
                awin[jj * 2 + 1] = *(const float4*)(p + 4);
            }
            stageB(nxt, c + 1);
            __builtin_amdgcn_sched_barrier(0);
        }

        const short* La = &lds[cur * BUF];
        const short* Lb = &lds[cur * BUF + ASZ];
        #pragma unroll
        for (int kk = 0; kk < 2; ++kk) {
            bf16x8 a[4];
            #pragma unroll
            for (int m = 0; m < 4; ++m)
                a[m] = *(const bf16x8*)(La + aoff[m][kk]);
            #pragma unroll
            for (int nt = 0; nt < NTW; ++nt) {
                const bf16x8 vbh = *(const bf16x8*)(Lb + boff[nt][kk]);
                const bf16x8 vbl = *(const bf16x8*)(Lb + boff[nt][kk] + NT * 16 * 64);
                #pragma unroll
                for (int m = 0; m < 4; ++m) {
                    acc[m][nt] = __builtin_amdgcn_mfma_f32_16x16x32_bf16(a[m], vbh, acc[m][nt], 0, 0, 0);
                    acc[m][nt] = __builtin_amdgcn_mfma_f32_16x16x32_bf16(a[m], vbl, acc[m][nt], 0, 0, 0);
                }
            }
        }

        if (c + 1 < NBK) {
            #pragma unroll
            for (int jj = 0; jj < 4; ++jj) {
                const float4 w0 = awin[jj * 2 + 0], w1 = awin[jj * 2 + 1];
                uint4 o;
                o.x = packbf(w0.x, w0.y); o.y = packbf(w0.z, w0.w);
                o.z = packbf(w1.x, w1.y); o.w = packbf(w1.z, w1.w);
                *((uint4*)&lds[nxt * BUF + (jj * 256 + tid) * 8]) = o;
            }
            asm volatile("s_waitcnt vmcnt(0)" ::: "memory");
            __builtin_amdgcn_s_barrier();
        }
    }
    __builtin_amdgcn_s_barrier();

    constexpr int EW = NT * 16 + 4;
    float* ep = (float*)lds;
    #pragma unroll
    for (int nt = 0; nt < NTW; ++nt) {
        const int lcol = wn * NTW * 16 + nt * 16 + lrow;
        const float bsc = bias[col0 + lcol];
        #pragma unroll
        for (int m = 0; m < 4; ++m)
            #pragma unroll
            for (int r = 0; r < 4; ++r)
                ep[(wm * 64 + m * 16 + quad * 4 + r) * EW + lcol] =
                    fmaxf(acc[m][nt][r] + bsc, 0.f);
    }
    __syncthreads();
    for (int g = tid; g < 128 * NT * 2; g += 256) {
        const int row = g / (NT * 2), u = g - row * (NT * 2);
        const int grow = bm + row;
        const float4 f0 = *(const float4*)(ep + row * EW + u * 8);
        const float4 f1 = *(const float4*)(ep + row * EW + u * 8 + 4);
        uint4 o;
        o.x = packbf(f0.x, f0.y); o.y = packbf(f0.z, f0.w);
        o.z = packbf(f1.x, f1.y); o.w = packbf(f1.z, f1.w);
        if (grow < M)
            *(uint4*)(Cb + (size_t)grow * ldcb + col0 + u * 8) = o;
    }
}

// ---------------- fused rel + classifier -----------------------------------
__global__ __launch_bounds__(256)
void gemm_relcls(const short* __restrict__ A1,         // h0b [M,128]
                 const short* __restrict__ A2,         // h2b [M,128]
                 const short* __restrict__ Wh, const short* __restrict__ Wl,
                 const float* __restrict__ rel_b,
                 const short* __restrict__ W1h, const short* __restrict__ W1l,
                 const float* __restrict__ cb1,
                 const short* __restrict__ W2h, const short* __restrict__ W2l,
                 const float* __restrict__ cb2,
                 float* __restrict__ out, int M) {
    constexpr int NT = 8, NTW = 4, NBK = 4, K = 256;
    constexpr int ASZ = 128 * 64;                 // 16 KB
    constexpr int BSZ = 2 * NT * 16 * 64;         // 32 KB
    constexpr int BUF = ASZ + BSZ;                // 24576 shorts
    __shared__ short lds[2 * BUF];                // 96 KB

    const int tid  = threadIdx.x;
    const int lane = tid & 63;
    const int wv   = tid >> 6;
    const int wm   = wv >> 1;
    const int wn   = wv & 1;
    const int bm   = blockIdx.x * 128;
    const int lrow = lane & 15;
    const int quad = lane >> 4;

    const int su = (tid & 7) ^ ((tid >> 3) & 7);
    const short* gsA1[4];
    const short* gsA2[4];
    #pragma unroll
    for (int jj = 0; jj < 4; ++jj) {
        const int rg = min(bm + jj * 32 + (tid >> 3), M - 1);
        gsA1[jj] = A1 + (size_t)rg * 128 + su * 8;
        gsA2[jj] = A2 + (size_t)rg * 128 + su * 8;
    }
    const short* gsB[NT];
    #pragma unroll
    for (int jj = 0; jj < NT; ++jj) {
        const int colIdx = jj * 32 + (tid >> 3);  // 0..255
        const bool ishi = colIdx < 128;
        const int cp = ishi ? colIdx : colIdx - 128;
        gsB[jj] = (ishi ? Wh : Wl) + (size_t)cp * K + su * 8;
    }
    auto stage = [&](int b, int c) {
        const int k = c * 64;
        #pragma unroll
        for (int jj = 0; jj < 4; ++jj) {
            const short* p = (k < 128) ? (gsA1[jj] + k) : (gsA2[jj] + (k - 128));
            gload_lds16(p, &lds[b * BUF + (jj * 256 + tid) * 8]);
        }
        #pragma unroll
        for (int jj = 0; jj < NT; ++jj)
            gload_lds16(gsB[jj] + k, &lds[b * BUF + ASZ + (jj * 256 + tid) * 8]);
    };

    int aoff[4][2], boff[NTW][2];
    #pragma unroll
    for (int m = 0; m < 4; ++m)
        #pragma unroll
        for (int kk = 0; kk < 2; ++kk)
            aoff[m][kk] = (wm * 64 + m * 16 + lrow) * 64 +
                          (((kk * 4 + quad) ^ (lrow & 7)) * 8);
    #pragma unroll
    for (int nt = 0; nt < NTW; ++nt)
        #pragma unroll
        for (int kk = 0; kk < 2; ++kk)
            boff[nt][kk] = (wn * 64 + nt * 16 + lrow) * 64 +
                           (((kk * 4 + quad) ^ (lrow & 7)) * 8);

    f32x4 acc[4][NTW];
    #pragma unroll
    for (int m = 0; m < 4; ++m)
        #pragma unroll
        for (int nt = 0; nt < NTW; ++nt)
            acc[m][nt] = (f32x4){0.f, 0.f, 0.f, 0.f};

    stage(0, 0);
    for (int c = 0; c < NBK; ++c) {
        const int b = c & 1;
        if (c + 1 < NBK) {
            stage(b ^ 1, c + 1);
            asm volatile("s_waitcnt vmcnt(12)" ::: "memory");
        } else {
            asm volatile("s_waitcnt vmcnt(0)" ::: "memory");
        }
        __builtin_amdgcn_s_barrier();

        const short* La = &lds[b * BUF];
        const short* Lb = &lds[b * BUF + ASZ];
        #pragma unroll
        for (int kk = 0; kk < 2; ++kk) {
            bf16x8 a[4];
            #pragma unroll
            for (int m = 0; m < 4; ++m)
                a[m] = *(const bf16x8*)(La + aoff[m][kk]);
            #pragma unroll
            for (int nt = 0; nt < NTW; ++nt) {
                const bf16x8 vbh = *(const bf16x8*)(Lb + boff[nt][kk]);
                const bf16x8 vbl = *(const bf16x8*)(Lb + boff[nt][kk] + 128 * 64);
                #pragma unroll
                for (int m = 0; m < 4; ++m) {
                    acc[m][nt] = __builtin_amdgcn_mfma_f32_16x16x32_bf16(a[m], vbh, acc[m][nt], 0, 0, 0);
                    acc[m][nt] = __builtin_amdgcn_mfma_f32_16x16x32_bf16(a[m], vbl, acc[m][nt], 0, 0, 0);
                }
            }
        }
        asm volatile("" ::: "memory");
        __builtin_amdgcn_s_barrier();
    }

    // ---- phase-1 epilogue: r = relu(acc + rel_b) -> rtile fp32 [128][132] --
    constexpr int EW1 = 132;
    float* rt = (float*)lds;
    #pragma unroll
    for (int nt = 0; nt < NTW; ++nt) {
        const int lcol = wn * 64 + nt * 16 + lrow;
        const float bsc = rel_b[lcol];
        #pragma unroll
        for (int m = 0; m < 4; ++m)
            #pragma unroll
            for (int r = 0; r < 4; ++r)
                rt[(wm * 64 + m * 16 + quad * 4 + r) * EW1 + lcol] =
                    fmaxf(acc[m][nt][r] + bsc, 0.f);
    }
    __syncthreads();

    // ---- phase 2: o1 = relu(r @ w1 + b1), K=128, 64 cols ----
    f32x4 acc2[4][2];
    #pragma unroll
    for (int m = 0; m < 4; ++m)
        #pragma unroll
        for (int nt = 0; nt < 2; ++nt)
            acc2[m][nt] = (f32x4){0.f, 0.f, 0.f, 0.f};
    #pragma unroll
    for (int kk = 0; kk < 4; ++kk) {
        bf16x8 b2h[2], b2l[2];
        #pragma unroll
        for (int nt = 0; nt < 2; ++nt) {
            const size_t cw = (size_t)(wn * 32 + nt * 16 + lrow) * 128 + kk * 32 + quad * 8;
            b2h[nt] = *(const bf16x8*)(W1h + cw);
            b2l[nt] = *(const bf16x8*)(W1l + cw);
        }
        #pragma unroll
        for (int m = 0; m < 4; ++m) {
            const float* pe = rt + (wm * 64 + m * 16 + lrow) * EW1 + kk * 32 + quad * 8;
            const float4 e0 = *(const float4*)pe;
            const float4 e1 = *(const float4*)(pe + 4);
            bf16x8 a;
            a[0] = (short)f2bf(e0.x); a[1] = (short)f2bf(e0.y);
            a[2] = (short)f2bf(e0.z); a[3] = (short)f2bf(e0.w);
            a[4] = (short)f2bf(e1.x); a[5] = (short)f2bf(e1.y);
            a[6] = (short)f2bf(e1.z); a[7] = (short)f2bf(e1.w);
            #pragma unroll
            for (int nt = 0; nt < 2; ++nt) {
                acc2[m][nt] = __builtin_amdgcn_mfma_f32_16x16x32_bf16(a, b2h[nt], acc2[m][nt], 0, 0, 0);
                acc2[m][nt] = __builtin_amdgcn_mfma_f32_16x16x32_bf16(a, b2l[nt], acc2[m][nt], 0, 0, 0);
            }
        }
    }
    __syncthreads();                              // all rtile reads done

    constexpr int EW2 = 68;
    float* ep2 = (float*)lds;                     // overwrites rtile
    #pragma unroll
    for (int nt = 0; nt < 2; ++nt) {
        const int lcol = wn * 32 + nt * 16 + lrow;
        const float bsc = cb1[lcol];
        #pragma unroll
        for (int m = 0; m < 4; ++m)
            #pragma unroll
            for (int r = 0; r < 4; ++r)
                ep2[(wm * 64 + m * 16 + quad * 4 + r) * EW2 + lcol] =
                    fmaxf(acc2[m][nt][r] + bsc, 0.f);
    }
    __syncthreads();

    // ---- phase 3: out = o1 @ w2 + b2, K=64, 32 cols ----
    const short* pB3h = W2h + (size_t)(wn * 16 + lrow) * 64 + quad * 8;
    const short* pB3l = W2l + (size_t)(wn * 16 + lrow) * 64 + quad * 8;
    f32x4 acc3[4];
    #pragma unroll
    for (int m = 0; m < 4; ++m) acc3[m] = (f32x4){0.f, 0.f, 0.f, 0.f};
    #pragma unroll
    for (int kk = 0; kk < 2; ++kk) {
        const bf16x8 bh = *(const bf16x8*)(pB3h + kk * 32);
        const bf16x8 bl = *(const bf16x8*)(pB3l + kk * 32);
        #pragma unroll
        for (int m = 0; m < 4; ++m) {
            const float* pe = ep2 + (wm * 64 + m * 16 + lrow) * EW2 + kk * 32 + quad * 8;
            const float4 e0 = *(const float4*)pe;
            const float4 e1 = *(const float4*)(pe + 4);
            bf16x8 a;
            a[0] = (short)f2bf(e0.x); a[1] = (short)f2bf(e0.y);
            a[2] = (short)f2bf(e0.z); a[3] = (short)f2bf(e0.w);
            a[4] = (short)f2bf(e1.x); a[5] = (short)f2bf(e1.y);
            a[6] = (short)f2bf(e1.z); a[7] = (short)f2bf(e1.w);
            acc3[m] = __builtin_amdgcn_mfma_f32_16x16x32_bf16(a, bh, acc3[m], 0, 0, 0);
            acc3[m] = __builtin_amdgcn_mfma_f32_16x16x32_bf16(a, bl, acc3[m], 0, 0, 0);
        }
    }

    constexpr int EW3 = 36;
    float* ep3 = (float*)lds + 128 * EW2;
    {
        const int lcol = wn * 16 + lrow;
        const float bsc = cb2[lcol];
        #pragma unroll
        for (int m = 0; m < 4; ++m)
            #pragma unroll
            for (int r = 0; r < 4; ++r)
                ep3[(wm * 64 + m * 16 + quad * 4 + r) * EW3 + lcol] =
                    acc3[m][r] + bsc;
    }
    __syncthreads();
    #pragma unroll
    for (int j = 0; j < 4; ++j) {
        const int g = tid + j * 256;
        const int row = g >> 3, u = g & 7;
        const int grow = bm + row;
        if (grow < M)
            *(float4*)(out + (size_t)grow * 32 + u * 4) =
                *(const float4*)(ep3 + row * EW3 + u * 4);
    }
}

// ---------------------------------------------------------------------------

extern "C" void kernel_launch(void* const* d_in, const int* in_sizes, int n_in,
                              void* d_out, int out_size, void* d_ws, size_t ws_size,
                              hipStream_t stream) {
    const float* sf    = (const float*)d_in[0];
    const float* mf    = (const float*)d_in[1];
    const int*   src   = (const int*)d_in[2];
    const int*   dst   = (const int*)d_in[3];
    const float* enc_w = (const float*)d_in[4];
    const float* enc_b = (const float*)d_in[5];
    const float* s0_ws = (const float*)d_in[6];
    const float* s0_wn = (const float*)d_in[7];
    const float* s0_b  = (const float*)d_in[8];
    const float* bn0_g = (const float*)d_in[9];
    const float* bn0_b = (const float*)d_in[10];
    const float* bn0_m = (const float*)d_in[11];
    const float* bn0_v = (const float*)d_in[12];
    const float* s1_ws = (const float*)d_in[13];
    const float* s1_wn = (const float*)d_in[14];
    const float* s1_b  = (const float*)d_in[15];
    const float* bn1_g = (const float*)d_in[16];
    const float* bn1_b = (const float*)d_in[17];
    const float* bn1_m = (const float*)d_in[18];
    const float* bn1_v = (const float*)d_in[19];
    const float* rel_w = (const float*)d_in[20];
    const float* rel_b = (const float*)d_in[21];
    const float* cw1   = (const float*)d_in[22];
    const float* cb1   = (const float*)d_in[23];
    const float* cw2   = (const float*)d_in[24];
    const float* cb2   = (const float*)d_in[25];
    float* out = (float*)d_out;

    const int nn = in_sizes[0] / 128;   // 100000
    const int ne = in_sizes[2];         // 800000
    const int nb = (nn + 1023) / 1024;  // scan blocks (98)

    short* h0b   = (short*)d_ws;                       // [nn,128] bf16
    short* xb    = h0b + (size_t)nn * 128;             // region [nn,512]
    float* st    = (float*)xb;                         // s1 fp32 [nn,128]
    short* h1b   = (short*)(st + (size_t)nn * 128);    // [nn,256] bf16
    short* agg0b = xb + (size_t)nn * 512;              // [nn,128]
    short* t1b   = agg0b + (size_t)nn * 128;           // [nn,128]
    short* h2b   = t1b + (size_t)nn * 128;             // [nn,128]
    int* deg    = (int*)(h2b + (size_t)nn * 128);
    int* rowptr = deg + nn;
    int* cursor = rowptr + nn + 1;
    int* part   = cursor + nn;                         // [nb+1]
    int* eidx   = part + nb + 1;
    short* wts = (short*)(eidx + ne);
    short* wt_enc_h = wts;                 short* wt_enc_l = wt_enc_h + 65536;   // [128][512]
    short* wt_s0_h  = wt_enc_l + 65536;    short* wt_s0_l  = wt_s0_h  + 65536;   // [256][256]
    short* wt_st_h  = wt_s0_l  + 65536;    short* wt_st_l  = wt_st_h  + 65536;   // [256][256]
    short* wt_rel_h = wt_st_l  + 65536;    short* wt_rel_l = wt_rel_h + 32768;   // [128][256]
    short* wt_c1_h  = wt_rel_l + 32768;    short* wt_c1_l  = wt_c1_h  + 8192;    // [64][128]
    short* wt_c2_h  = wt_c1_l  + 8192;     short* wt_c2_l  = wt_c2_h  + 2048;    // [32][64]

    const dim3 blk(256);
    const dim3 blk512(512);
    const int gM = (nn + 127) / 128;    // 782 row-blocks

    // --- CSR build (parallel scan) ---
    hipMemsetAsync(deg, 0, (size_t)nn * 4, stream);
    count_deg <<<dim3((ne + 255) / 256), blk, 0, stream>>>(dst, deg, ne);
    scan_block<<<dim3(nb), dim3(1024), 0, stream>>>(deg, rowptr, part, nn);
    scan_part <<<dim3(1),  dim3(1024), 0, stream>>>(part, nb);
    scan_add  <<<dim3((nn + 255) / 256), blk, 0, stream>>>(part, rowptr, cursor, nn, nb);
    fill_edges<<<dim3((ne + 255) / 256), blk, 0, stream>>>(src, dst, cursor, eidx, ne);

    // --- weight prep (fused, 1 launch) ---
    prep_all<<<dim3(936), blk, 0, stream>>>(
        enc_w, s0_ws, s0_wn, s1_ws, s1_wn, rel_w, cw1, cw2,
        wt_enc_h, wt_enc_l, wt_s0_h, wt_s0_l, wt_st_h, wt_st_l,
        wt_rel_h, wt_rel_l, wt_c1_h, wt_c1_l, wt_c2_h, wt_c2_l);

    // --- h0 = relu(concat(sf,mf) @ enc_w + enc_b) -> h0b bf16 (fused) ---
    gemm_enc<<<dim3(2, gM), blk, 0, stream>>>(
        sf, mf, wt_enc_h, wt_enc_l, enc_b, h0b, 128, nn);

    // --- agg0 = mean_neigh(h0b) -> agg0b bf16 ---
    agg_mean_bb<<<dim3((nn + 3) / 4), blk, 0, stream>>>(
        h0b, rowptr, eidx, agg0b, nn);

    // --- h1 = relu(bn0(h0@ws0 + agg0@wn0 + b0)) -> h1b bf16 (wide) ---
    gemm_w<128, 128><<<dim3(2, gM), blk512, 0, stream>>>(
        h0b, 128, agg0b, 128, wt_s0_h, wt_s0_l, s0_b,
        bn0_g, bn0_b, bn0_m, bn0_v, 1,
        nullptr, 0, 0, h1b, 0, 256, nn);

    // --- [s1 | t1] = h1 @ [ws1 | wn1]; s1 fp32 -> st, t1 bf16 -> t1b ---
    gemm_w<256, 0><<<dim3(2, gM), blk512, 0, stream>>>(
        h1b, 256, nullptr, 0, wt_st_h, wt_st_l, nullptr,
        nullptr, nullptr, nullptr, nullptr, 0,
        st, 128, 128, t1b, 128, 128, nn);

    // --- h2 = relu(bn1(s1 + mean_neigh(t1) + b1)) -> h2b bf16 ---
    agg_combine_bb<<<dim3((nn + 3) / 4), blk, 0, stream>>>(
        t1b, rowptr, eidx, st, s1_b,
        bn1_g, bn1_b, bn1_m, bn1_v, h2b, nn);

    // --- out = fused rel + cls1 + cls2 ---
    gemm_relcls<<<dim3(gM), blk, 0, stream>>>(
        h0b, h2b, wt_rel_h, wt_rel_l, rel_b,
        wt_c1_h, wt_c1_l, cb1, wt_c2_h, wt_c2_l, cb2, out, nn);
}